// Round 8
// baseline (270.343 us; speedup 1.0000x reference)
//
#include <hip/hip_runtime.h>
#include <math.h>

#define NROWS 8192   // BATCH*NODE
#define DIM   128
#define FEAT  256
#define BK    128
#define NT    (NROWS / BK)   // 64 K-tiles in gemm1

typedef __attribute__((ext_vector_type(8))) __bf16 bf16x8;
typedef __attribute__((ext_vector_type(8))) unsigned short u16x8;
typedef __attribute__((ext_vector_type(4))) unsigned short u16x4;
typedef __attribute__((ext_vector_type(4))) float f32x4;

__device__ __forceinline__ float bf2f(unsigned short h) {
  return __uint_as_float(((unsigned)h) << 16);
}
__device__ __forceinline__ unsigned short f2bf(float f) {
  unsigned u = __float_as_uint(f);
  return (unsigned short)((u + 0x7fff + ((u >> 16) & 1)) >> 16);  // RNE
}
__device__ __forceinline__ void async16(const void* g, void* l) {
  __builtin_amdgcn_global_load_lds(
      (const __attribute__((address_space(1))) void*)g,
      (__attribute__((address_space(3))) void*)l, 16, 0, 0);
}
__device__ __forceinline__ f32x4 mfma16(bf16x8 a, bf16x8 b, f32x4 c) {
  return __builtin_amdgcn_mfma_f32_16x16x32_bf16(a, b, c, 0, 0, 0);
}
__device__ __forceinline__ float ldp(const void* p, int i, int is32) {
  return is32 ? ((const float*)p)[i] : bf2f(((const unsigned short*)p)[i]);
}

// ---------------------------------------------------------------------------
// dtype detection + zero both stats sets
// ---------------------------------------------------------------------------
__global__ void detect_kernel(const unsigned short* __restrict__ L,
                              int* __restrict__ flag,
                              float* __restrict__ stats)
{
  for (int i = threadIdx.x; i < 1024; i += 256) stats[i] = 0.f;
  __shared__ int cnt;
  if (threadIdx.x == 0) cnt = 0;
  __syncthreads();
  int c = 0;
  for (int i = 0; i < 16; i++) {
    unsigned short s = L[2 * (threadIdx.x + 256 * i)];
    int e = (s >> 7) & 0xFF;
    if (e >= 192) c++;
  }
  atomicAdd(&cnt, c);
  __syncthreads();
  if (threadIdx.x == 0) *flag = (cnt > 16) ? 1 : 0;
}

// ---------------------------------------------------------------------------
// fused first transpose: raw input -> inpc (bf16 copy), x0 (elu'd), xT
// (128x8192 transposed elu'd), + x-part column stats (cols 0..127).
// ---------------------------------------------------------------------------
__global__ __launch_bounds__(256) void trans_kernel(
    const void* __restrict__ src, unsigned short* __restrict__ xT,
    unsigned short* __restrict__ x0, unsigned short* __restrict__ inpc,
    float* __restrict__ stats, const int* __restrict__ flag)
{
  __shared__ __align__(16) unsigned short T[128 * 136];  // pad 128->136
  const int tid = threadIdx.x;
  const int r0 = blockIdx.x * 128;
  const int is32 = *flag;
  #pragma unroll
  for (int i = 0; i < 8; i++) {
    const int c = tid + 256 * i;           // 0..2047
    const int rr = c >> 4, cg = c & 15;
    const size_t gidx = (size_t)(r0 + rr) * DIM + cg * 8;
    u16x8 v;
    if (is32) {
      const float* s = (const float*)src + gidx;
      f32x4 a = *(const f32x4*)s, b = *(const f32x4*)(s + 4);
      #pragma unroll
      for (int e = 0; e < 4; e++) { v[e] = f2bf(a[e]); v[e + 4] = f2bf(b[e]); }
    } else {
      v = *(const u16x8*)((const unsigned short*)src + gidx);
    }
    *(u16x8*)(inpc + gidx) = v;            // raw copy for residual
    #pragma unroll
    for (int e = 0; e < 8; e++) {
      float f = bf2f(v[e]);
      f = f > 0.f ? f : expm1f(f);
      v[e] = f2bf(f);
    }
    *(u16x8*)(x0 + gidx) = v;              // elu'd x for gemm2
    *(u16x8*)(T + rr * 136 + cg * 8) = v;
  }
  __syncthreads();
  #pragma unroll
  for (int i = 0; i < 8; i++) {
    const int c = tid + 256 * i;
    const int n = c >> 4, mg = c & 15;     // n = feature, mg = 8-row group
    u16x8 v;
    float s = 0.f, q = 0.f;
    #pragma unroll
    for (int e = 0; e < 8; e++) {
      unsigned short h = T[(mg * 8 + e) * 136 + n];
      v[e] = h;
      float f = bf2f(h);
      s += f; q += f * f;
    }
    *(u16x8*)(xT + (size_t)n * NROWS + r0 + mg * 8) = v;
    #pragma unroll
    for (int off = 1; off < 16; off <<= 1) {
      s += __shfl_xor(s, off, 16);
      q += __shfl_xor(q, off, 16);
    }
    if ((tid & 15) == 0) {
      atomicAdd(&stats[n], s);
      atomicAdd(&stats[256 + n], q);
    }
  }
}

// ---------------------------------------------------------------------------
// GEMM1 (f32-L path): Lx[m0:+32, :] = L[m0:+32, :] @ x  (full K = 8192)
// A-fragments loaded DIRECTLY from global f32 in MFMA lane layout
// (row = m0 + i*16 + ln, k = kq*32 + quad*8), cvt'd in-register, 1-tile
// register prefetch -> A never touches LDS (no ds_write, no A frag reads).
// Wave decomposition (m,n,k) = (1,2,4): wave (kq = w>>1, nh = w&1) computes
// M=32 x N=64 x K=32 per step: 8 MFMA, 8 indep acc chains, B frag reads
// exactly 1x the B tile. B triple-buffered via global_load_lds with counted
// vmcnt(4) + raw s_barrier (never drains newest tile). K-quarter partials
// reduced through a 4-step LDS tree in the epilogue.
// LDS B 16B chunks XOR-swizzled: phys p = (kg&8)|((kg&7)^(row&7)) both sides.
// ---------------------------------------------------------------------------
__device__ __forceinline__ void gemm1_f32_body(
    const float* __restrict__ Lf, const unsigned short* __restrict__ xT,
    unsigned short* __restrict__ Lxb, float* __restrict__ stats,
    unsigned short* __restrict__ BsBase)
{
  const int tid  = threadIdx.x;          // 0..511
  const int lane = tid & 63;
  const int wave = tid >> 6;             // 0..7
  const int kq = wave >> 1, nh = wave & 1;   // K-quarter x N-half
  const int ln = lane & 15, quad = lane >> 4;
  const int m0 = blockIdx.x * 32;

  // B staging coords: 2048 chunks (128 rows x 16), 4/thread
  int brow[4], bkg[4];
  #pragma unroll
  for (int i = 0; i < 4; i++) {
    const int c = tid + (i << 9);
    brow[i] = c >> 4;
    const int p = c & 15;
    bkg[i] = (p & 8) | ((p & 7) ^ (brow[i] & 7));
  }

  unsigned short* c0 = BsBase;
  unsigned short* c1 = BsBase + 128 * 128;
  unsigned short* c2 = BsBase + 2 * 128 * 128;

  f32x4 acc[2][4];
  #pragma unroll
  for (int i = 0; i < 2; i++)
    #pragma unroll
    for (int j = 0; j < 4; j++)
      acc[i][j] = (f32x4){0.f, 0.f, 0.f, 0.f};

  // A frag base: row m0+ln (i=0) / +16 rows (i=1), k offset kq*32 + quad*8
  const size_t Afb = (size_t)(m0 + ln) * NROWS + kq * 32 + quad * 8;
  f32x4 pA0, pA1, pA2, pA3;            // raw f32 prefetch (tile t+1)
  bf16x8 afc0, afc1;                   // cvt'd frags (tile t)

  auto issueB = [&](int kt, unsigned short* Bbuf) {
    const size_t koff = (size_t)kt * BK;
    #pragma unroll
    for (int i = 0; i < 4; i++) {
      const int c = tid + (i << 9);
      async16(xT + (size_t)brow[i] * NROWS + koff + bkg[i] * 8, Bbuf + c * 8);
    }
  };
  auto issueAF = [&](int kt) {
    const float* b = Lf + Afb + (size_t)kt * BK;
    pA0 = *(const f32x4*)b;
    pA1 = *(const f32x4*)(b + 4);
    pA2 = *(const f32x4*)(b + (size_t)16 * NROWS);
    pA3 = *(const f32x4*)(b + (size_t)16 * NROWS + 4);
  };
  auto cvtA = [&]() {
    union { u16x8 u; bf16x8 b; } cv0, cv1;
    #pragma unroll
    for (int e = 0; e < 4; e++) {
      cv0.u[e] = f2bf(pA0[e]); cv0.u[e + 4] = f2bf(pA1[e]);
      cv1.u[e] = f2bf(pA2[e]); cv1.u[e + 4] = f2bf(pA3[e]);
    }
    afc0 = cv0.b; afc1 = cv1.b;
  };
  auto compute = [&](const unsigned short* Bbuf) {
    const int kga = kq * 4 + quad;
    #pragma unroll
    for (int j = 0; j < 4; j++) {
      const int nr = nh * 64 + j * 16 + ln;
      bf16x8 bf = *(const bf16x8*)(Bbuf + nr * 128 +
                     ((kga & 8) | ((kga & 7) ^ (nr & 7))) * 8);
      acc[0][j] = mfma16(afc0, bf, acc[0][j]);
      acc[1][j] = mfma16(afc1, bf, acc[1][j]);
    }
  };

  // ---- prologue: A(0) frags + B tiles 0,1 in flight ----
  issueAF(0);
  issueB(0, c0);
  issueB(1, c1);
  asm volatile("s_waitcnt vmcnt(4) lgkmcnt(0)" ::: "memory");  // A0,B0 done
  cvtA();
  __builtin_amdgcn_s_barrier();

  // ---- main: tiles 0..61 ----
  for (int t = 0; t < 62; ++t) {
    issueAF(t + 1);                 // A frags for next tile (regs)
    issueB(t + 2, c2);              // B two tiles ahead (LDS)
    compute(c0);                    // tile t
    asm volatile("s_waitcnt vmcnt(4) lgkmcnt(0)" ::: "memory");  // A(t+1),B(t+1)
    cvtA();
    __builtin_amdgcn_s_barrier();
    unsigned short* tb = c0; c0 = c1; c1 = c2; c2 = tb;
  }

  // ---- tail: tiles 62, 63 ----
  issueAF(63);
  compute(c0);                      // tile 62
  asm volatile("s_waitcnt vmcnt(4) lgkmcnt(0)" ::: "memory");   // B(63) done
  cvtA();                           // compiler guards A(63) regs
  __builtin_amdgcn_s_barrier();
  compute(c1);                      // tile 63
  __syncthreads();                  // drain before Bs reuse as E

  // ---- epilogue: 4-way K-quarter reduce into f32 LDS tile (in Bs) ----
  float* E = (float*)BsBase;        // 32 x 128 f32 = 16 KB
  for (int g = 0; g < 4; g++) {
    if (kq == g) {
      #pragma unroll
      for (int i = 0; i < 2; i++)
        #pragma unroll
        for (int j = 0; j < 4; j++)
          #pragma unroll
          for (int r = 0; r < 4; r++) {
            float* p = &E[(i * 16 + quad * 4 + r) * 128 + nh * 64 + j * 16 + ln];
            if (g == 0) *p = acc[i][j][r];
            else        *p += acc[i][j][r];
          }
    }
    __syncthreads();
  }
  {  // coalesced bf16 store of Lx
    const int row = tid >> 4, cc0 = (tid & 15) * 8;
    u16x8 o;
    #pragma unroll
    for (int e = 0; e < 8; e++) o[e] = f2bf(E[row * 128 + cc0 + e]);
    *(u16x8*)(Lxb + (size_t)(m0 + row) * DIM + cc0) = o;
  }
  if (tid < 128) {  // column stats (f32 values), features 128..255
    float s = 0.f, q = 0.f;
    #pragma unroll
    for (int r = 0; r < 32; r++) {
      const float v = E[r * 128 + tid];
      s += v; q += v * v;
    }
    atomicAdd(&stats[128 + tid], s);
    atomicAdd(&stats[384 + tid], q);
  }
}

// ---------------------------------------------------------------------------
// GEMM1 (bf16-L fallback): round-7 proven body, unchanged.
// ---------------------------------------------------------------------------
__device__ __forceinline__ void gemm1_bf16_body(
    const unsigned short* __restrict__ Lh, const unsigned short* __restrict__ xT,
    unsigned short* __restrict__ Lxb, float* __restrict__ stats,
    unsigned short* __restrict__ AsBase, unsigned short* __restrict__ BsBase)
{
  const int tid  = threadIdx.x;          // 0..511
  const int lane = tid & 63;
  const int wave = tid >> 6;             // 0..7
  const int kh = wave >> 2, wq = wave & 3;   // K-half x N-quad
  const int ln = lane & 15, quad = lane >> 4;
  const int m0 = blockIdx.x * 32;

  const int arow = tid >> 4, ap = tid & 15;
  const int akg = (ap & 8) | ((ap & 7) ^ (arow & 7));
  const size_t Abase = (size_t)(m0 + arow) * NROWS + akg * 8;

  int brow[4], bkg[4];
  #pragma unroll
  for (int i = 0; i < 4; i++) {
    const int c = tid + (i << 9);
    brow[i] = c >> 4;
    const int p = c & 15;
    bkg[i] = (p & 8) | ((p & 7) ^ (brow[i] & 7));
  }

  unsigned short* a0 = AsBase;
  unsigned short* a1 = AsBase + 32 * 128;
  unsigned short* a2 = AsBase + 2 * 32 * 128;
  unsigned short* c0 = BsBase;
  unsigned short* c1 = BsBase + 128 * 128;
  unsigned short* c2 = BsBase + 2 * 128 * 128;

  f32x4 acc[2][2];
  #pragma unroll
  for (int i = 0; i < 2; i++)
    #pragma unroll
    for (int j = 0; j < 2; j++)
      acc[i][j] = (f32x4){0.f, 0.f, 0.f, 0.f};

  auto issueB = [&](int kt, unsigned short* Bbuf) {
    const size_t koff = (size_t)kt * BK;
    #pragma unroll
    for (int i = 0; i < 4; i++) {
      const int c = tid + (i << 9);
      async16(xT + (size_t)brow[i] * NROWS + koff + bkg[i] * 8, Bbuf + c * 8);
    }
  };
  auto issueA16 = [&](int kt, unsigned short* Abuf) {
    async16(Lh + Abase + (size_t)kt * BK, Abuf + arow * 128 + ap * 8);
  };
  auto compute = [&](const unsigned short* Abuf, const unsigned short* Bbuf) {
    #pragma unroll
    for (int s = 0; s < 2; s++) {
      const int kga = kh * 8 + s * 4 + quad;
      const int sw8 = ((kga & 8) | ((kga & 7) ^ (ln & 7))) * 8;
      bf16x8 af0 = *(const bf16x8*)(Abuf + ln * 128 + sw8);
      bf16x8 af1 = *(const bf16x8*)(Abuf + (16 + ln) * 128 + sw8);
      bf16x8 bf0 = *(const bf16x8*)(Bbuf + (wq * 32 + ln) * 128 + sw8);
      bf16x8 bf1 = *(const bf16x8*)(Bbuf + (wq * 32 + 16 + ln) * 128 + sw8);
      acc[0][0] = mfma16(af0, bf0, acc[0][0]);
      acc[0][1] = mfma16(af0, bf1, acc[0][1]);
      acc[1][0] = mfma16(af1, bf0, acc[1][0]);
      acc[1][1] = mfma16(af1, bf1, acc[1][1]);
    }
  };
  auto waitbar = [&]() {
    asm volatile("s_waitcnt vmcnt(5) lgkmcnt(0)" ::: "memory");
    __builtin_amdgcn_s_barrier();
  };

  issueB(0, c0); issueA16(0, a0);
  issueB(1, c1); issueA16(1, a1);
  waitbar();

  for (int p = 0; p < 31; ++p) {
    const int t = 2 * p;
    issueB(t + 2, c2); issueA16(t + 2, a2);
    compute(a0, c0);
    waitbar();
    issueB(t + 3, c0); issueA16(t + 3, a0);
    compute(a1, c1);
    waitbar();
    unsigned short* tB = c2; c2 = c1; c1 = c0; c0 = tB;
    unsigned short* tA = a2; a2 = a1; a1 = a0; a0 = tA;
  }
  compute(a0, c0);
  __syncthreads();
  compute(a1, c1);
  __syncthreads();

  float* E = (float*)AsBase;
  if (kh == 0) {
    #pragma unroll
    for (int i = 0; i < 2; i++)
      #pragma unroll
      for (int j = 0; j < 2; j++)
        #pragma unroll
        for (int r = 0; r < 4; r++)
          E[(i * 16 + quad * 4 + r) * 128 + wq * 32 + j * 16 + ln] =
              acc[i][j][r];
  }
  __syncthreads();
  if (kh == 1) {
    #pragma unroll
    for (int i = 0; i < 2; i++)
      #pragma unroll
      for (int j = 0; j < 2; j++)
        #pragma unroll
        for (int r = 0; r < 4; r++)
          E[(i * 16 + quad * 4 + r) * 128 + wq * 32 + j * 16 + ln] +=
              acc[i][j][r];
  }
  __syncthreads();
  {
    const int row = tid >> 4, cc0 = (tid & 15) * 8;
    u16x8 o;
    #pragma unroll
    for (int e = 0; e < 8; e++) o[e] = f2bf(E[row * 128 + cc0 + e]);
    *(u16x8*)(Lxb + (size_t)(m0 + row) * DIM + cc0) = o;
  }
  if (tid < 128) {
    float s = 0.f, q = 0.f;
    #pragma unroll
    for (int r = 0; r < 32; r++) {
      const float v = E[r * 128 + tid];
      s += v; q += v * v;
    }
    atomicAdd(&stats[128 + tid], s);
    atomicAdd(&stats[384 + tid], q);
  }
}

__global__ __launch_bounds__(512) void gemm1_fused(
    const void* __restrict__ Lraw, const unsigned short* __restrict__ xT,
    unsigned short* __restrict__ Lxb, float* __restrict__ stats,
    const int* __restrict__ flag)
{
  __shared__ __align__(16) unsigned short As[3 * 32 * 128];    // 24 KB
  __shared__ __align__(16) unsigned short Bs[3 * 128 * 128];   // 96 KB
  if (*flag) gemm1_f32_body((const float*)Lraw, xT, Lxb, stats, Bs);
  else       gemm1_bf16_body((const unsigned short*)Lraw, xT, Lxb, stats,
                             As, Bs);
}

// ---------------------------------------------------------------------------
// fold BN into FC; reads raw-dtype params directly (flag)
// ---------------------------------------------------------------------------
__global__ void prep_kernel(const float* __restrict__ stats,
                            const void* __restrict__ gamma,
                            const void* __restrict__ beta,
                            const void* __restrict__ w,
                            const void* __restrict__ bias,
                            unsigned short* __restrict__ weff,
                            float* __restrict__ beff,
                            const int* __restrict__ flag)
{
  const int is32 = *flag;
  const int k = blockIdx.x;   // 0..127
  const int j = threadIdx.x;  // 0..255
  const float inv = 1.f / 8192.f;
  float mu = stats[j] * inv;
  float var = fmaxf(stats[256 + j] * inv - mu * mu, 0.f);
  float s = ldp(gamma, j, is32) * rsqrtf(var + 1e-5f);
  float wv = ldp(w, k * FEAT + j, is32);
  weff[(size_t)k * FEAT + j] = f2bf(wv * s);
  float term = (ldp(beta, j, is32) - mu * s) * wv;
  __shared__ float red[256];
  red[j] = term;
  __syncthreads();
  for (int off = 128; off > 0; off >>= 1) {
    if (j < off) red[j] += red[j + off];
    __syncthreads();
  }
  if (j == 0) beff[k] = ldp(bias, k, is32) + red[0];
}

// ---------------------------------------------------------------------------
// GEMM2: out = [x | Lxb] @ weff.T + beff
// mode0: elu -> bf16 x1, plus fused transpose write xT and x1 column stats.
// mode1: + resid -> d_out (bf16 or f32 per flag). M-tile 32, grid 256.
// ---------------------------------------------------------------------------
__global__ __launch_bounds__(256) void gemm2_fc(
    const unsigned short* __restrict__ xb,    // 8192x128
    const unsigned short* __restrict__ Lxb,   // 8192x128
    const unsigned short* __restrict__ weff,  // 128x256
    const float* __restrict__ beff,           // 128
    const unsigned short* __restrict__ resid, // inp_c (mode1) or nullptr
    void* __restrict__ outv,
    unsigned short* __restrict__ xTout,       // mode0 only
    float* __restrict__ statsOut,             // mode0 only
    int mode, const int* __restrict__ flag)
{
  __shared__ __align__(16) unsigned short As[32 * 264];
  const int is32 = *flag;
  const int tid = threadIdx.x;
  const int lane = tid & 63, wave = tid >> 6;
  const int m0 = blockIdx.x * 32;

  #pragma unroll
  for (int i = 0; i < 4; i++) {
    const int c = tid + 256 * i;        // 0..1023 (32 rows x 32 chunks)
    const int mr = c >> 5, ch = c & 31;
    const unsigned short* src =
        (ch < 16) ? (xb  + (size_t)(m0 + mr) * DIM + ch * 8)
                  : (Lxb + (size_t)(m0 + mr) * DIM + (ch - 16) * 8);
    *(u16x8*)(As + mr * 264 + ch * 8) = *(const u16x8*)src;
  }
  __syncthreads();

  const int ln = lane & 15, quad = lane >> 4;
  const int nq = wave * 32;
  f32x4 acc[2][2];
  #pragma unroll
  for (int i = 0; i < 2; i++)
    #pragma unroll
    for (int j = 0; j < 2; j++)
      acc[i][j] = (f32x4){0.f, 0.f, 0.f, 0.f};

  #pragma unroll
  for (int ks = 0; ks < 8; ks++) {
    bf16x8 af[2], bfr[2];
    #pragma unroll
    for (int i = 0; i < 2; i++)
      af[i] = *(const bf16x8*)(As + (i * 16 + ln) * 264 + ks * 32 + quad * 8);
    #pragma unroll
    for (int j = 0; j < 2; j++)
      bfr[j] = *(const bf16x8*)(weff + (size_t)(nq + j * 16 + ln) * FEAT +
                                ks * 32 + quad * 8);
    #pragma unroll
    for (int i = 0; i < 2; i++)
      #pragma unroll
      for (int j = 0; j < 2; j++)
        acc[i][j] = mfma16(af[i], bfr[j], acc[i][j]);
  }

  #pragma unroll
  for (int j = 0; j < 2; j++) {
    const int gn = nq + j * 16 + ln;
    const float bb = beff[gn];
    float s = 0.f, q = 0.f;
    #pragma unroll
    for (int i = 0; i < 2; i++) {
      u16x4 pk;
      #pragma unroll
      for (int r = 0; r < 4; r++) {
        const int gm = m0 + i * 16 + quad * 4 + r;
        float v = acc[i][j][r] + bb;
        const size_t idx = (size_t)gm * DIM + gn;
        if (mode == 0) {
          v = v > 0.f ? v : expm1f(v);
          const unsigned short h = f2bf(v);
          ((unsigned short*)outv)[idx] = h;
          pk[r] = h;
          const float hv = bf2f(h);
          s += hv; q += hv * hv;
        } else {
          v += bf2f(resid[idx]);
          if (is32) ((float*)outv)[idx] = v;
          else      ((unsigned short*)outv)[idx] = f2bf(v);
        }
      }
      if (mode == 0)
        *(u16x4*)(xTout + (size_t)gn * NROWS + m0 + i * 16 + quad * 4) = pk;
    }
    if (mode == 0) {
      s += __shfl_xor(s, 16); q += __shfl_xor(q, 16);
      s += __shfl_xor(s, 32); q += __shfl_xor(q, 32);
      if (quad == 0) {
        atomicAdd(&statsOut[gn], s);
        atomicAdd(&statsOut[256 + gn], q);
      }
    }
  }
}

// ---------------------------------------------------------------------------
extern "C" void kernel_launch(void* const* d_in, const int* in_sizes, int n_in,
                              void* d_out, int out_size, void* d_ws, size_t ws_size,
                              hipStream_t stream) {
  const void* Lm   = d_in[0];
  // d_in[1] = mask (unused)
  const void* inp  = d_in[2];
  const void* bn0g = d_in[3];
  const void* bn0b = d_in[4];
  const void* fc0w = d_in[5];
  const void* fc0b = d_in[6];
  const void* bn1g = d_in[7];
  const void* bn1b = d_in[8];
  const void* fc1w = d_in[9];
  const void* fc1b = d_in[10];

  char* ws = (char*)d_ws;
  unsigned short* xT   = (unsigned short*)(ws);                  // 2 MB
  unsigned short* x0   = (unsigned short*)(ws + (2ull << 20));   // 2 MB
  unsigned short* Lxb  = (unsigned short*)(ws + (4ull << 20));   // 2 MB
  unsigned short* x1   = (unsigned short*)(ws + (6ull << 20));   // 2 MB
  unsigned short* inpc = (unsigned short*)(ws + (8ull << 20));   // 2 MB
  float*          stats= (float*)         (ws + (10ull << 20));  // 2x512 f32
  int*            flag = (int*)           (ws + (10ull << 20) + 8192);
  float*          beff = (float*)         (ws + (10ull << 20) + 12288);
  unsigned short* weff = (unsigned short*)(ws + (10ull << 20) + 16384); // 64KB

  detect_kernel<<<1, 256, 0, stream>>>((const unsigned short*)Lm, flag, stats);

  // ---- block 0 ----
  trans_kernel<<<64, 256, 0, stream>>>(inp, xT, x0, inpc, stats, flag);
  gemm1_fused<<<256, 512, 0, stream>>>(Lm, xT, Lxb, stats, flag);
  prep_kernel<<<128, 256, 0, stream>>>(stats, bn0g, bn0b, fc0w, fc0b,
                                       weff, beff, flag);
  gemm2_fc<<<256, 256, 0, stream>>>(x0, Lxb, weff, beff, nullptr, x1,
                                    xT, stats + 512, 0, flag);

  // ---- block 1 ----
  gemm1_fused<<<256, 512, 0, stream>>>(Lm, xT, Lxb, stats + 512, flag);
  prep_kernel<<<128, 256, 0, stream>>>(stats + 512, bn1g, bn1b, fc1w, fc1b,
                                       weff, beff, flag);
  gemm2_fc<<<256, 256, 0, stream>>>(x1, Lxb, weff, beff, inpc, d_out,
                                    nullptr, nullptr, 1, flag);
}

// Round 9
// 203.145 us; speedup vs baseline: 1.3308x; 1.3308x over previous
//
#include <hip/hip_runtime.h>
#include <math.h>

#define NROWS 8192   // BATCH*NODE
#define DIM   128
#define FEAT  256
#define BK    128
#define NT    (NROWS / BK)   // 64 K-tiles in gemm1

typedef __attribute__((ext_vector_type(8))) __bf16 bf16x8;
typedef __attribute__((ext_vector_type(8))) unsigned short u16x8;
typedef __attribute__((ext_vector_type(4))) unsigned short u16x4;
typedef __attribute__((ext_vector_type(4))) float f32x4;

__device__ __forceinline__ float bf2f(unsigned short h) {
  return __uint_as_float(((unsigned)h) << 16);
}
__device__ __forceinline__ unsigned short f2bf(float f) {
  unsigned u = __float_as_uint(f);
  return (unsigned short)((u + 0x7fff + ((u >> 16) & 1)) >> 16);  // RNE
}
__device__ __forceinline__ void async16(const void* g, void* l) {
  __builtin_amdgcn_global_load_lds(
      (const __attribute__((address_space(1))) void*)g,
      (__attribute__((address_space(3))) void*)l, 16, 0, 0);
}
__device__ __forceinline__ f32x4 mfma16(bf16x8 a, bf16x8 b, f32x4 c) {
  return __builtin_amdgcn_mfma_f32_16x16x32_bf16(a, b, c, 0, 0, 0);
}
__device__ __forceinline__ float ldp(const void* p, int i, int is32) {
  return is32 ? ((const float*)p)[i] : bf2f(((const unsigned short*)p)[i]);
}

// ---------------------------------------------------------------------------
// dtype detection + zero both stats sets
// ---------------------------------------------------------------------------
__global__ void detect_kernel(const unsigned short* __restrict__ L,
                              int* __restrict__ flag,
                              float* __restrict__ stats)
{
  for (int i = threadIdx.x; i < 1024; i += 256) stats[i] = 0.f;
  __shared__ int cnt;
  if (threadIdx.x == 0) cnt = 0;
  __syncthreads();
  int c = 0;
  for (int i = 0; i < 16; i++) {
    unsigned short s = L[2 * (threadIdx.x + 256 * i)];
    int e = (s >> 7) & 0xFF;
    if (e >= 192) c++;
  }
  atomicAdd(&cnt, c);
  __syncthreads();
  if (threadIdx.x == 0) *flag = (cnt > 16) ? 1 : 0;
}

// ---------------------------------------------------------------------------
// fused first transpose (64 blocks x 128 rows): raw input -> inpc (bf16),
// x0 (elu'd), xT (128x8192 transposed elu'd), x-part column stats (atomics
// into pre-zeroed stats). Side duty (blocks 0..7): convert FC weights to
// bf16 into wb (w0 | w1, 65536 elems).
// ---------------------------------------------------------------------------
__global__ __launch_bounds__(256) void trans_kernel(
    const void* __restrict__ src, unsigned short* __restrict__ xT,
    unsigned short* __restrict__ x0, unsigned short* __restrict__ inpc,
    float* __restrict__ stats, const int* __restrict__ flag,
    const void* __restrict__ w0raw, const void* __restrict__ w1raw,
    unsigned short* __restrict__ wb)
{
  __shared__ __align__(16) unsigned short T[128 * 136];  // pad 128->136
  const int tid = threadIdx.x;
  const int r0 = blockIdx.x * 128;
  const int is32 = *flag;

  // weight conversion side-duty: blocks 0..7 cover 65536 elems (w0|w1)
  if (blockIdx.x < 8) {
    const int base = blockIdx.x * 8192;
    for (int i = tid; i < 8192; i += 256) {
      const int g = base + i;
      const float v = (g < 32768) ? ldp(w0raw, g, is32)
                                  : ldp(w1raw, g - 32768, is32);
      wb[g] = f2bf(v);
    }
  }

  #pragma unroll
  for (int i = 0; i < 8; i++) {
    const int c = tid + 256 * i;           // 0..2047
    const int rr = c >> 4, cg = c & 15;
    const size_t gidx = (size_t)(r0 + rr) * DIM + cg * 8;
    u16x8 v;
    if (is32) {
      const float* s = (const float*)src + gidx;
      f32x4 a = *(const f32x4*)s, b = *(const f32x4*)(s + 4);
      #pragma unroll
      for (int e = 0; e < 4; e++) { v[e] = f2bf(a[e]); v[e + 4] = f2bf(b[e]); }
    } else {
      v = *(const u16x8*)((const unsigned short*)src + gidx);
    }
    *(u16x8*)(inpc + gidx) = v;            // raw copy for residual
    #pragma unroll
    for (int e = 0; e < 8; e++) {
      float f = bf2f(v[e]);
      f = f > 0.f ? f : expm1f(f);
      v[e] = f2bf(f);
    }
    *(u16x8*)(x0 + gidx) = v;              // elu'd x for gemm2
    *(u16x8*)(T + rr * 136 + cg * 8) = v;
  }
  __syncthreads();
  #pragma unroll
  for (int i = 0; i < 8; i++) {
    const int c = tid + 256 * i;
    const int n = c >> 4, mg = c & 15;     // n = feature, mg = 8-row group
    u16x8 v;
    float s = 0.f, q = 0.f;
    #pragma unroll
    for (int e = 0; e < 8; e++) {
      unsigned short h = T[(mg * 8 + e) * 136 + n];
      v[e] = h;
      float f = bf2f(h);
      s += f; q += f * f;
    }
    *(u16x8*)(xT + (size_t)n * NROWS + r0 + mg * 8) = v;
    #pragma unroll
    for (int off = 1; off < 16; off <<= 1) {
      s += __shfl_xor(s, off, 16);
      q += __shfl_xor(q, off, 16);
    }
    if ((tid & 15) == 0) {
      atomicAdd(&stats[n], s);
      atomicAdd(&stats[256 + n], q);
    }
  }
}

// ---------------------------------------------------------------------------
// GEMM1 fused (round-7 proven body + writeA hoisted off the critical path):
// Lx[m0:m0+32, :] = L[m0:m0+32, :] @ x  (full K = 8192)
// Depth-2 pipeline: triple-buffered B (and A) tiles, counted s_waitcnt
// vmcnt(N) + raw s_barrier per K-step (never drains newest tile; all loads
// issued TWO tiles ahead — the r8 one-tile-ahead variant exposed HBM
// latency and regressed 2.4x).
// Wave decomposition: 8 waves = 2 K-halves (kh) x 4 N-quads (wq); each wave:
// 8 MFMA from 8 frag reads, 4 indep acc chains. K-halves reduced through
// the epilogue LDS tile. writeA (f32 path) placed BEFORE compute — its
// destination buffer is only read after the next barrier.
// LDS 16B chunks XOR-swizzled: phys p = (kg&8)|((kg&7)^(row&7)) both sides.
// ---------------------------------------------------------------------------
template <int IS32>
__device__ __forceinline__ void gemm1_body(
    const void* __restrict__ Lraw, const unsigned short* __restrict__ xT,
    unsigned short* __restrict__ Lxb, float* __restrict__ stats,
    unsigned short* __restrict__ AsBase, unsigned short* __restrict__ BsBase)
{
  const int tid  = threadIdx.x;          // 0..511
  const int lane = tid & 63;
  const int wave = tid >> 6;             // 0..7
  const int kh = wave >> 2, wq = wave & 3;   // K-half x N-quad
  const int ln = lane & 15, quad = lane >> 4;
  const int m0 = blockIdx.x * 32;

  // A staging coords: 512 chunks of 16B (32 rows x 16 chunks), 1/thread
  const int arow = tid >> 4, ap = tid & 15;
  const int akg = (ap & 8) | ((ap & 7) ^ (arow & 7));   // global k-group
  const float*          Lf = (const float*)Lraw;
  const unsigned short* Lh = (const unsigned short*)Lraw;
  const size_t Abase = (size_t)(m0 + arow) * NROWS + akg * 8;

  // B staging coords: 2048 chunks (128 rows x 16), 4/thread
  int brow[4], bkg[4];
  #pragma unroll
  for (int i = 0; i < 4; i++) {
    const int c = tid + (i << 9);
    brow[i] = c >> 4;
    const int p = c & 15;
    bkg[i] = (p & 8) | ((p & 7) ^ (brow[i] & 7));
  }

  unsigned short* a0 = AsBase;
  unsigned short* a1 = AsBase + 32 * 128;
  unsigned short* a2 = AsBase + 2 * 32 * 128;
  unsigned short* c0 = BsBase;
  unsigned short* c1 = BsBase + 128 * 128;
  unsigned short* c2 = BsBase + 2 * 128 * 128;

  f32x4 acc[2][2];
  #pragma unroll
  for (int i = 0; i < 2; i++)
    #pragma unroll
    for (int j = 0; j < 2; j++)
      acc[i][j] = (f32x4){0.f, 0.f, 0.f, 0.f};

  auto issueB = [&](int kt, unsigned short* Bbuf) {
    const size_t koff = (size_t)kt * BK;
    #pragma unroll
    for (int i = 0; i < 4; i++) {
      const int c = tid + (i << 9);
      async16(xT + (size_t)brow[i] * NROWS + koff + bkg[i] * 8, Bbuf + c * 8);
    }
  };
  auto loadA = [&](int kt, f32x4& r0, f32x4& r1) {
    const float* s = Lf + Abase + (size_t)kt * BK;
    r0 = *(const f32x4*)s;
    r1 = *(const f32x4*)(s + 4);
  };
  auto issueA16 = [&](int kt, unsigned short* Abuf) {
    async16(Lh + Abase + (size_t)kt * BK, Abuf + arow * 128 + ap * 8);
  };
  auto writeA = [&](const f32x4& r0, const f32x4& r1, unsigned short* Abuf) {
    u16x8 o;
    #pragma unroll
    for (int e = 0; e < 4; e++) { o[e] = f2bf(r0[e]); o[e + 4] = f2bf(r1[e]); }
    *(u16x8*)(Abuf + arow * 128 + ap * 8) = o;
  };
  auto compute = [&](const unsigned short* Abuf, const unsigned short* Bbuf) {
    #pragma unroll
    for (int s = 0; s < 2; s++) {
      const int kga = kh * 8 + s * 4 + quad;
      const int sw8 = ((kga & 8) | ((kga & 7) ^ (ln & 7))) * 8;
      // all frag rows are ln mod 8 (row offsets 0,16 and wq*32,+16 are ==0 mod 8)
      bf16x8 af0 = *(const bf16x8*)(Abuf + ln * 128 + sw8);
      bf16x8 af1 = *(const bf16x8*)(Abuf + (16 + ln) * 128 + sw8);
      bf16x8 bf0 = *(const bf16x8*)(Bbuf + (wq * 32 + ln) * 128 + sw8);
      bf16x8 bf1 = *(const bf16x8*)(Bbuf + (wq * 32 + 16 + ln) * 128 + sw8);
      acc[0][0] = mfma16(af0, bf0, acc[0][0]);
      acc[0][1] = mfma16(af0, bf1, acc[0][1]);
      acc[1][0] = mfma16(af1, bf0, acc[1][0]);
      acc[1][1] = mfma16(af1, bf1, acc[1][1]);
    }
  };
  auto waitbar = [&]() {
    // retire everything except the newest tile's vmem group (6 f32 / 5 bf16)
    if (IS32) asm volatile("s_waitcnt vmcnt(6) lgkmcnt(0)" ::: "memory");
    else      asm volatile("s_waitcnt vmcnt(5) lgkmcnt(0)" ::: "memory");
    __builtin_amdgcn_s_barrier();
  };

  f32x4 e0, e1, o0, o1;   // A f32 reg sets (even-tile / odd-tile destined)

  // ---- prologue: tiles 0 and 1 in flight ----
  issueB(0, c0);
  if (IS32) loadA(0, e0, e1); else issueA16(0, a0);
  issueB(1, c1);
  if (IS32) loadA(1, o0, o1); else issueA16(1, a1);
  if (IS32) writeA(e0, e1, a0);   // auto vmcnt wait covers tile-0 A regs
  waitbar();

  // ---- main: 31 pairs, tiles 0..61, prefetch 2 ahead ----
  for (int p = 0; p < 31; ++p) {
    const int t = 2 * p;
    // even body: tile t (reads a0/c0)
    issueB(t + 2, c2);
    if (IS32) loadA(t + 2, e0, e1); else issueA16(t + 2, a2);
    if (IS32) writeA(o0, o1, a1);   // A(t+1) -> a1; nobody reads a1 this step
    compute(a0, c0);
    waitbar();
    // odd body: tile t+1 (reads a1/c1)
    issueB(t + 3, c0);
    if (IS32) loadA(t + 3, o0, o1); else issueA16(t + 3, a0);
    if (IS32) writeA(e0, e1, a2);   // A(t+2) -> a2 (future buffer)
    compute(a1, c1);
    waitbar();
    // rotate buffers: (c0,c1,c2) <- (c2,c0,c1)
    unsigned short* tB = c2; c2 = c1; c1 = c0; c0 = tB;
    unsigned short* tA = a2; a2 = a1; a1 = a0; a0 = tA;
  }

  // ---- tail: tiles 62, 63 (already prefetched) ----
  if (IS32) writeA(o0, o1, a1);     // A(63)
  compute(a0, c0);                  // tile 62
  __syncthreads();                  // drains remaining tile-63 vmem
  compute(a1, c1);                  // tile 63
  __syncthreads();

  // ---- epilogue: cross-K-half reduce into f32 LDS tile (reuses A bufs) ----
  float* E = (float*)AsBase;        // 32 x 128 f32 = 16 KB
  if (kh == 0) {
    #pragma unroll
    for (int i = 0; i < 2; i++)
      #pragma unroll
      for (int j = 0; j < 2; j++)
        #pragma unroll
        for (int r = 0; r < 4; r++)
          E[(i * 16 + quad * 4 + r) * 128 + wq * 32 + j * 16 + ln] =
              acc[i][j][r];
  }
  __syncthreads();
  if (kh == 1) {
    #pragma unroll
    for (int i = 0; i < 2; i++)
      #pragma unroll
      for (int j = 0; j < 2; j++)
        #pragma unroll
        for (int r = 0; r < 4; r++)
          E[(i * 16 + quad * 4 + r) * 128 + wq * 32 + j * 16 + ln] +=
              acc[i][j][r];
  }
  __syncthreads();
  {  // coalesced bf16 store of Lx
    const int row = tid >> 4, cc0 = (tid & 15) * 8;
    u16x8 o;
    #pragma unroll
    for (int e = 0; e < 8; e++) o[e] = f2bf(E[row * 128 + cc0 + e]);
    *(u16x8*)(Lxb + (size_t)(m0 + row) * DIM + cc0) = o;
  }
  if (tid < 128) {  // column stats (f32 values), features 128..255
    float s = 0.f, q = 0.f;
    #pragma unroll
    for (int r = 0; r < 32; r++) {
      const float v = E[r * 128 + tid];
      s += v; q += v * v;
    }
    atomicAdd(&stats[128 + tid], s);
    atomicAdd(&stats[384 + tid], q);
  }
}

__global__ __launch_bounds__(512) void gemm1_fused(
    const void* __restrict__ Lraw, const unsigned short* __restrict__ xT,
    unsigned short* __restrict__ Lxb, float* __restrict__ stats,
    const int* __restrict__ flag)
{
  __shared__ __align__(16) unsigned short As[3 * 32 * 128];    // 24 KB
  __shared__ __align__(16) unsigned short Bs[3 * 128 * 128];   // 96 KB
  if (*flag) gemm1_body<1>(Lraw, xT, Lxb, stats, As, Bs);
  else       gemm1_body<0>(Lraw, xT, Lxb, stats, As, Bs);
}

// ---------------------------------------------------------------------------
// GEMM2 with fused BN-fold (no prep kernel; round-5 proven logic):
//   out = ((h - mu) * s) @ w^T + (beta @ w^T + bias)
// stats are COMPLETE sums (atomics upstream): mu/var from 2 direct loads per
// feature — no reduce loop. BN applied on A-tile at staging; raw bf16
// weights as B frags; beta-matvec bias computed in-block (tiny).
// mode0: elu -> bf16 x1, fused transpose write xT, x1 column stats (atomics
//        into pre-zeroed statsOut). mode1: + resid -> d_out (bf16/f32 per
//        flag). M-tile 32, grid 256, 256 threads (4 waves).
// ---------------------------------------------------------------------------
__global__ __launch_bounds__(256) void gemm2_fc(
    const unsigned short* __restrict__ xb,    // 8192x128
    const unsigned short* __restrict__ Lxb,   // 8192x128
    const unsigned short* __restrict__ wb,    // 128x256 bf16 raw weights
    const void* __restrict__ gamma, const void* __restrict__ beta,
    const void* __restrict__ bias,
    const float* __restrict__ stats,          // 512 complete sums/sumsq
    const unsigned short* __restrict__ resid, // inp_c (mode1) or nullptr
    void* __restrict__ outv,
    unsigned short* __restrict__ xTout,       // mode0 only
    float* __restrict__ statsOut,             // mode0 only
    int mode, const int* __restrict__ flag)
{
  __shared__ __align__(16) unsigned short As[32 * 264];
  __shared__ float sS[256], sMS[256], bred[256], bv[128];
  const int is32 = *flag;
  const int tid = threadIdx.x;
  const int lane = tid & 63, wave = tid >> 6;
  const int m0 = blockIdx.x * 32;

  // ---- per-feature BN scale from complete sums (no loop) ----
  {
    const int j = tid;  // 0..255
    const float inv = 1.f / 8192.f;
    const float mu = stats[j] * inv;
    const float var = fmaxf(stats[256 + j] * inv - mu * mu, 0.f);
    const float sj = ldp(gamma, j, is32) * rsqrtf(var + 1e-5f);
    sS[j] = sj;
    sMS[j] = mu * sj;
  }
  // ---- beta matvec for bias: thread t: k = t&127, half = t>>7 ----
  {
    const int k = tid & 127, half = tid >> 7;
    float a = 0.f;
    #pragma unroll
    for (int jj = 0; jj < 128; jj += 8) {
      u16x8 wv = *(const u16x8*)(wb + k * 256 + half * 128 + jj);
      #pragma unroll
      for (int e = 0; e < 8; e++)
        a += ldp(beta, half * 128 + jj + e, is32) * bf2f(wv[e]);
    }
    bred[tid] = a;
  }
  __syncthreads();
  if (tid < 128)
    bv[tid] = ldp(bias, tid, is32) + bred[tid] + bred[tid + 128];

  // ---- stage A tile with BN transform ----
  #pragma unroll
  for (int i = 0; i < 4; i++) {
    const int c = tid + 256 * i;        // 0..1023 (32 rows x 32 chunks)
    const int mr = c >> 5, ch = c & 31;
    const unsigned short* src =
        (ch < 16) ? (xb  + (size_t)(m0 + mr) * DIM + ch * 8)
                  : (Lxb + (size_t)(m0 + mr) * DIM + (ch - 16) * 8);
    u16x8 v = *(const u16x8*)src;
    const int j0 = ch * 8;              // feature index base (0..255)
    #pragma unroll
    for (int e = 0; e < 8; e++) {
      const float f = bf2f(v[e]);
      v[e] = f2bf(f * sS[j0 + e] - sMS[j0 + e]);
    }
    *(u16x8*)(As + mr * 264 + ch * 8) = v;
  }
  __syncthreads();   // also orders bv writes before epilogue reads

  const int ln = lane & 15, quad = lane >> 4;
  const int nq = wave * 32;
  f32x4 acc[2][2];
  #pragma unroll
  for (int i = 0; i < 2; i++)
    #pragma unroll
    for (int j = 0; j < 2; j++)
      acc[i][j] = (f32x4){0.f, 0.f, 0.f, 0.f};

  #pragma unroll
  for (int ks = 0; ks < 8; ks++) {
    bf16x8 af[2], bfr[2];
    #pragma unroll
    for (int i = 0; i < 2; i++)
      af[i] = *(const bf16x8*)(As + (i * 16 + ln) * 264 + ks * 32 + quad * 8);
    #pragma unroll
    for (int j = 0; j < 2; j++)
      bfr[j] = *(const bf16x8*)(wb + (size_t)(nq + j * 16 + ln) * FEAT +
                                ks * 32 + quad * 8);
    #pragma unroll
    for (int i = 0; i < 2; i++)
      #pragma unroll
      for (int j = 0; j < 2; j++)
        acc[i][j] = mfma16(af[i], bfr[j], acc[i][j]);
  }

  #pragma unroll
  for (int j = 0; j < 2; j++) {
    const int gn = nq + j * 16 + ln;
    const float bb = bv[gn];
    float s = 0.f, q = 0.f;
    #pragma unroll
    for (int i = 0; i < 2; i++) {
      u16x4 pk;
      #pragma unroll
      for (int r = 0; r < 4; r++) {
        const int gm = m0 + i * 16 + quad * 4 + r;
        float v = acc[i][j][r] + bb;
        const size_t idx = (size_t)gm * DIM + gn;
        if (mode == 0) {
          v = v > 0.f ? v : expm1f(v);
          const unsigned short h = f2bf(v);
          ((unsigned short*)outv)[idx] = h;
          pk[r] = h;
          const float hv = bf2f(h);
          s += hv; q += hv * hv;
        } else {
          v += bf2f(resid[idx]);
          if (is32) ((float*)outv)[idx] = v;
          else      ((unsigned short*)outv)[idx] = f2bf(v);
        }
      }
      if (mode == 0)
        *(u16x4*)(xTout + (size_t)gn * NROWS + m0 + i * 16 + quad * 4) = pk;
    }
    if (mode == 0) {
      s += __shfl_xor(s, 16); q += __shfl_xor(q, 16);
      s += __shfl_xor(s, 32); q += __shfl_xor(q, 32);
      if (quad == 0) {
        atomicAdd(&statsOut[gn], s);
        atomicAdd(&statsOut[256 + gn], q);
      }
    }
  }
}

// ---------------------------------------------------------------------------
extern "C" void kernel_launch(void* const* d_in, const int* in_sizes, int n_in,
                              void* d_out, int out_size, void* d_ws, size_t ws_size,
                              hipStream_t stream) {
  const void* Lm   = d_in[0];
  // d_in[1] = mask (unused)
  const void* inp  = d_in[2];
  const void* bn0g = d_in[3];
  const void* bn0b = d_in[4];
  const void* fc0w = d_in[5];
  const void* fc0b = d_in[6];
  const void* bn1g = d_in[7];
  const void* bn1b = d_in[8];
  const void* fc1w = d_in[9];
  const void* fc1b = d_in[10];

  char* ws = (char*)d_ws;
  unsigned short* xT   = (unsigned short*)(ws);                  // 2 MB
  unsigned short* x0   = (unsigned short*)(ws + (2ull << 20));   // 2 MB
  unsigned short* Lxb  = (unsigned short*)(ws + (4ull << 20));   // 2 MB
  unsigned short* x1   = (unsigned short*)(ws + (6ull << 20));   // 2 MB
  unsigned short* inpc = (unsigned short*)(ws + (8ull << 20));   // 2 MB
  float*          stats= (float*)         (ws + (10ull << 20));  // 2x512 f32
  int*            flag = (int*)           (ws + (10ull << 20) + 8192);
  unsigned short* wb   = (unsigned short*)(ws + (10ull << 20) + 16384); // 128KB

  detect_kernel<<<1, 256, 0, stream>>>((const unsigned short*)Lm, flag, stats);

  // ---- block 0 ----
  trans_kernel<<<64, 256, 0, stream>>>(inp, xT, x0, inpc, stats, flag,
                                       fc0w, fc1w, wb);
  gemm1_fused<<<256, 512, 0, stream>>>(Lm, xT, Lxb, stats, flag);
  gemm2_fc<<<256, 256, 0, stream>>>(x0, Lxb, wb, bn0g, bn0b, fc0b,
                                    stats, nullptr, x1,
                                    xT, stats + 512, 0, flag);

  // ---- block 1 ----
  gemm1_fused<<<256, 512, 0, stream>>>(Lm, xT, Lxb, stats + 512, flag);
  gemm2_fc<<<256, 256, 0, stream>>>(x1, Lxb, wb + 32768, bn1g, bn1b, fc1b,
                                    stats + 512, inpc, d_out,
                                    nullptr, nullptr, 1, flag);
}